// Round 1
// baseline (254.384 us; speedup 1.0000x reference)
//
#include <hip/hip_runtime.h>
#include <hip/hip_bf16.h>

// Problem: out[128,12288] = [ clip(x[:, :6144] @ R, 0, 1) | zeros ]
// M=128, K=N=6144. Memory-bound on streaming R (151 MB fp32).

#define NPIX 12288
#define NV   6144
#define MR   128
#define BNW  32      // N columns per block
#define KST  128     // K per pipeline step
#define KCH  3072    // K per chunk (2 chunks)
#define NSI  24      // KCH / KST

typedef __attribute__((ext_vector_type(8))) short bf16x8;
typedef __attribute__((ext_vector_type(4))) float f32x4;
typedef __attribute__((ext_vector_type(4))) unsigned u32x4;

__device__ __forceinline__ unsigned pk2(float lo, float hi) {
    __hip_bfloat162 h = __float22bfloat162_rn(make_float2(lo, hi));
    union { __hip_bfloat162 h; unsigned u; } v; v.h = h; return v.u;
}

__device__ __forceinline__ bf16x8 cvt8(f32x4 a, f32x4 b) {
    union { unsigned u[4]; bf16x8 v; } r;
    r.u[0] = pk2(a[0], a[1]); r.u[1] = pk2(a[2], a[3]);
    r.u[2] = pk2(b[0], b[1]); r.u[3] = pk2(b[2], b[3]);
    return r.v;
}

// ---- prep: convert x[:, :6144] fp32 -> bf16 A[128][6144] in ws ----
__global__ __launch_bounds__(256) void prep_kernel(const float* __restrict__ x,
                                                   unsigned short* __restrict__ abf) {
    int q = blockIdx.x * 256 + threadIdx.x;   // 0 .. 98303 (exact)
    int m = q / (NV / 8);
    int r = q % (NV / 8);
    int k = r * 8;
    const float* src = x + (size_t)m * NPIX + k;
    f32x4 a = *(const f32x4*)(src);
    f32x4 b = *(const f32x4*)(src + 4);
    u32x4 o;
    o[0] = pk2(a[0], a[1]); o[1] = pk2(a[2], a[3]);
    o[2] = pk2(b[0], b[1]); o[3] = pk2(b[2], b[3]);
    *(u32x4*)(abf + (size_t)m * NV + k) = o;
}

// ---- staging helpers ----
__device__ __forceinline__ void sload(const float*& bptr, float2 (&r)[8]) {
    #pragma unroll
    for (int gi = 0; gi < 4; ++gi) {
        const float* p = bptr + (size_t)(gi * 32) * NV;
        r[2 * gi]     = *(const float2*)(p);        // row kq+gi*32   (even k)
        r[2 * gi + 1] = *(const float2*)(p + NV);   // row kq+gi*32+1 (odd k)
    }
    bptr += (size_t)KST * NV;
}

__device__ __forceinline__ void wstage(unsigned char* buf, const float2 (&r)[8],
                                       int kq, int nq, int sw0, int sw1) {
    #pragma unroll
    for (int gi = 0; gi < 4; ++gi) {
        unsigned lo = pk2(r[2 * gi].x, r[2 * gi + 1].x);  // col nq  : (k,k+1)
        unsigned hi = pk2(r[2 * gi].y, r[2 * gi + 1].y);  // col nq+1: (k,k+1)
        const int kbyte = (kq + gi * 32) * 2;
        *(unsigned*)(buf + nq * 256       + (kbyte ^ sw0)) = lo;
        *(unsigned*)(buf + (nq + 1) * 256 + (kbyte ^ sw1)) = hi;
    }
}

template<bool BF16A>
__device__ __forceinline__ void compute_step(const unsigned char* buf,
        const unsigned short* __restrict__ A, const float* __restrict__ X,
        size_t arow0, size_t arow1, int ln, int lg, f32x4 (&acc)[2][2]) {
    bf16x8 afr[2][4];
    #pragma unroll
    for (int ks = 0; ks < 4; ++ks) {
        if (BF16A) {
            afr[0][ks] = *(const bf16x8*)(A + arow0 + ks * 32);
            afr[1][ks] = *(const bf16x8*)(A + arow1 + ks * 32);
        } else {
            f32x4 p0 = *(const f32x4*)(X + arow0 + ks * 32);
            f32x4 p1 = *(const f32x4*)(X + arow0 + ks * 32 + 4);
            afr[0][ks] = cvt8(p0, p1);
            f32x4 q0 = *(const f32x4*)(X + arow1 + ks * 32);
            f32x4 q1 = *(const f32x4*)(X + arow1 + ks * 32 + 4);
            afr[1][ks] = cvt8(q0, q1);
        }
    }
    const int swn = (ln & 7) << 4;
    #pragma unroll
    for (int nt = 0; nt < 2; ++nt) {
        const int rowb = (nt * 16 + ln) * 256;
        #pragma unroll
        for (int ks = 0; ks < 4; ++ks) {
            bf16x8 bfr = *(const bf16x8*)(buf + rowb + (((lg * 16) + ks * 64) ^ swn));
            acc[0][nt] = __builtin_amdgcn_mfma_f32_16x16x32_bf16(afr[0][ks], bfr, acc[0][nt], 0, 0, 0);
            acc[1][nt] = __builtin_amdgcn_mfma_f32_16x16x32_bf16(afr[1][ks], bfr, acc[1][nt], 0, 0, 0);
        }
    }
}

// ---- GEMM: grid = 192 n-stripes x 2 K-chunks = 384 blocks, 256 threads ----
template<bool BF16A>
__global__ __launch_bounds__(256, 2) void gemm_kernel(const float* __restrict__ X,
        const unsigned short* __restrict__ A, const float* __restrict__ R,
        float* __restrict__ out) {
    __shared__ unsigned char Bs0[32 * 256];  // [n:32][k:128] bf16, XOR-swizzled
    __shared__ unsigned char Bs1[32 * 256];

    const int tid = threadIdx.x;
    const int w = tid >> 6;          // wave 0..3 -> M rows [32w, 32w+32)
    const int l = tid & 63;
    const int ln = l & 15, lg = l >> 4;
    const int nb = blockIdx.x >> 1, chunk = blockIdx.x & 1;
    const int n0 = nb * BNW;
    const int kbase = chunk * KCH;

    // B staging map: thread -> (k pair, n pair)
    const int kq = (tid >> 4) * 2;   // 0..30 even
    const int nq = (tid & 15) * 2;   // 0..30 even
    const float* bptr = R + (size_t)(kbase + kq) * NV + (n0 + nq);
    const int sw0 = (nq & 7) << 4;
    const int sw1 = ((nq + 1) & 7) << 4;

    size_t arow0, arow1;
    if (BF16A) {
        arow0 = (size_t)(w * 32 + ln) * NV + kbase + lg * 8;
        arow1 = arow0 + (size_t)16 * NV;
    } else {
        arow0 = (size_t)(w * 32 + ln) * NPIX + kbase + lg * 8;
        arow1 = arow0 + (size_t)16 * NPIX;
    }

    f32x4 acc[2][2];
    #pragma unroll
    for (int a = 0; a < 2; ++a)
        #pragma unroll
        for (int b = 0; b < 2; ++b) {
            acc[a][b][0] = 0.f; acc[a][b][1] = 0.f;
            acc[a][b][2] = 0.f; acc[a][b][3] = 0.f;
        }

    float2 ring0[8], ring1[8];
    sload(bptr, ring0);                       // step 0
    sload(bptr, ring1);                       // step 1
    wstage(Bs0, ring0, kq, nq, sw0, sw1);     // stage step 0
    __syncthreads();

    #pragma unroll 1
    for (int it = 0; it < NSI / 2; ++it) {
        const int s = it * 2;
        if (s + 2 < NSI) sload(bptr, ring0);                  // prefetch step s+2
        compute_step<BF16A>(Bs0, A, X, arow0, arow1, ln, lg, acc);  // step s
        arow0 += KST; arow1 += KST;
        wstage(Bs1, ring1, kq, nq, sw0, sw1);                 // stage step s+1
        __syncthreads();
        if (s + 3 < NSI) sload(bptr, ring1);                  // prefetch step s+3
        compute_step<BF16A>(Bs1, A, X, arow0, arow1, ln, lg, acc);  // step s+1
        arow0 += KST; arow1 += KST;
        if (s + 2 < NSI) wstage(Bs0, ring0, kq, nq, sw0, sw1);// stage step s+2
        __syncthreads();
    }

    // store raw partial sums: chunk c -> out columns [c*6144, c*6144+6144)
    #pragma unroll
    for (int mt = 0; mt < 2; ++mt) {
        const int mbase = w * 32 + mt * 16 + lg * 4;
        #pragma unroll
        for (int nt = 0; nt < 2; ++nt) {
            const size_t cb = (size_t)chunk * NV + n0 + nt * 16 + ln;
            #pragma unroll
            for (int j = 0; j < 4; ++j)
                out[(size_t)(mbase + j) * NPIX + cb] = acc[mt][nt][j];
        }
    }
}

// ---- reduce: out[:, :6144] = clip(P0 + P1), out[:, 6144:] = 0 ----
__global__ __launch_bounds__(256) void reduce_kernel(float* __restrict__ out) {
    int q = blockIdx.x * 256 + threadIdx.x;   // 0 .. 196607 (exact)
    int m = q / (NV / 4);
    int r = q % (NV / 4);
    size_t base = (size_t)m * NPIX + r * 4;
    f32x4 a = *(f32x4*)(out + base);
    f32x4 b = *(f32x4*)(out + base + NV);
    f32x4 c, z;
    #pragma unroll
    for (int i = 0; i < 4; ++i) {
        float v = a[i] + b[i];
        c[i] = fminf(fmaxf(v, 0.f), 1.f);
        z[i] = 0.f;
    }
    *(f32x4*)(out + base) = c;
    *(f32x4*)(out + base + NV) = z;
}

extern "C" void kernel_launch(void* const* d_in, const int* in_sizes, int n_in,
                              void* d_out, int out_size, void* d_ws, size_t ws_size,
                              hipStream_t stream) {
    const float* x = (const float*)d_in[0];   // (8,16,12288) fp32 -> A rows [128][12288]
    const float* R = (const float*)d_in[1];   // (6144,6144) fp32
    float* out = (float*)d_out;               // (8,16,12288) fp32

    const bool use_ws = ws_size >= (size_t)MR * NV * 2;
    if (use_ws) {
        unsigned short* abf = (unsigned short*)d_ws;
        prep_kernel<<<(MR * NV / 8) / 256, 256, 0, stream>>>(x, abf);
        gemm_kernel<true><<<(NV / BNW) * 2, 256, 0, stream>>>(x, abf, R, out);
    } else {
        gemm_kernel<false><<<(NV / BNW) * 2, 256, 0, stream>>>(x, nullptr, R, out);
    }
    reduce_kernel<<<(MR * NV / 4) / 256, 256, 0, stream>>>(out);
}

// Round 2
// 247.778 us; speedup vs baseline: 1.0267x; 1.0267x over previous
//
#include <hip/hip_runtime.h>
#include <hip/hip_bf16.h>

// Problem: out[128,12288] = [ clip(x[:, :6144] @ R, 0, 1) | zeros ]
// M=128, K=N=6144. Memory-bound on streaming R (151 MB fp32).
// Strategy: bf16 MFMA, K split into 8 chunks for occupancy (1536 blocks),
// fp32 partial sums parked in out (2 slots) + ws (6 slots), then reduce+clip.

#define NPIX 12288
#define NV   6144
#define MR   128
#define BNW  32      // N columns per block
#define KST  128     // K per pipeline step
#define NSTR (NV / BNW)          // 192 n-stripes
#define PARTF ((size_t)MR * NV)  // floats per partial slot (786432 = 3MB)

typedef __attribute__((ext_vector_type(8))) short bf16x8;
typedef __attribute__((ext_vector_type(4))) float f32x4;
typedef __attribute__((ext_vector_type(4))) unsigned u32x4;

__device__ __forceinline__ unsigned pk2(float lo, float hi) {
    __hip_bfloat162 h = __float22bfloat162_rn(make_float2(lo, hi));
    union { __hip_bfloat162 h; unsigned u; } v; v.h = h; return v.u;
}

__device__ __forceinline__ bf16x8 cvt8(f32x4 a, f32x4 b) {
    union { unsigned u[4]; bf16x8 v; } r;
    r.u[0] = pk2(a[0], a[1]); r.u[1] = pk2(a[2], a[3]);
    r.u[2] = pk2(b[0], b[1]); r.u[3] = pk2(b[2], b[3]);
    return r.v;
}

// ---- prep: convert x[:, :6144] fp32 -> bf16 A[128][6144] in ws ----
__global__ __launch_bounds__(256) void prep_kernel(const float* __restrict__ x,
                                                   unsigned short* __restrict__ abf) {
    int q = blockIdx.x * 256 + threadIdx.x;   // 0 .. 98303 (exact)
    int m = q / (NV / 8);
    int r = q % (NV / 8);
    int k = r * 8;
    const float* src = x + (size_t)m * NPIX + k;
    f32x4 a = *(const f32x4*)(src);
    f32x4 b = *(const f32x4*)(src + 4);
    u32x4 o;
    o[0] = pk2(a[0], a[1]); o[1] = pk2(a[2], a[3]);
    o[2] = pk2(b[0], b[1]); o[3] = pk2(b[2], b[3]);
    *(u32x4*)(abf + (size_t)m * NV + k) = o;
}

// ---- staging helpers ----
__device__ __forceinline__ void sload(const float*& bptr, float2 (&r)[8]) {
    #pragma unroll
    for (int gi = 0; gi < 4; ++gi) {
        const float* p = bptr + (size_t)(gi * 32) * NV;
        r[2 * gi]     = *(const float2*)(p);        // row kq+gi*32   (even k)
        r[2 * gi + 1] = *(const float2*)(p + NV);   // row kq+gi*32+1 (odd k)
    }
    bptr += (size_t)KST * NV;
}

__device__ __forceinline__ void wstage(unsigned char* buf, const float2 (&r)[8],
                                       int kq, int nq, int sw0, int sw1) {
    #pragma unroll
    for (int gi = 0; gi < 4; ++gi) {
        unsigned lo = pk2(r[2 * gi].x, r[2 * gi + 1].x);  // col nq  : (k,k+1)
        unsigned hi = pk2(r[2 * gi].y, r[2 * gi + 1].y);  // col nq+1: (k,k+1)
        const int kbyte = (kq + gi * 32) * 2;
        *(unsigned*)(buf + nq * 256       + (kbyte ^ sw0)) = lo;
        *(unsigned*)(buf + (nq + 1) * 256 + (kbyte ^ sw1)) = hi;
    }
}

template<bool BF16A>
__device__ __forceinline__ void compute_step(const unsigned char* buf,
        const unsigned short* __restrict__ A, const float* __restrict__ X,
        size_t arow0, size_t arow1, int ln, int lg, f32x4 (&acc)[2][2]) {
    bf16x8 afr[2][4];
    #pragma unroll
    for (int ks = 0; ks < 4; ++ks) {
        if (BF16A) {
            afr[0][ks] = *(const bf16x8*)(A + arow0 + ks * 32);
            afr[1][ks] = *(const bf16x8*)(A + arow1 + ks * 32);
        } else {
            f32x4 p0 = *(const f32x4*)(X + arow0 + ks * 32);
            f32x4 p1 = *(const f32x4*)(X + arow0 + ks * 32 + 4);
            afr[0][ks] = cvt8(p0, p1);
            f32x4 q0 = *(const f32x4*)(X + arow1 + ks * 32);
            f32x4 q1 = *(const f32x4*)(X + arow1 + ks * 32 + 4);
            afr[1][ks] = cvt8(q0, q1);
        }
    }
    const int swn = (ln & 7) << 4;
    #pragma unroll
    for (int nt = 0; nt < 2; ++nt) {
        const int rowb = (nt * 16 + ln) * 256;
        #pragma unroll
        for (int ks = 0; ks < 4; ++ks) {
            bf16x8 bfr = *(const bf16x8*)(buf + rowb + (((lg * 16) + ks * 64) ^ swn));
            acc[0][nt] = __builtin_amdgcn_mfma_f32_16x16x32_bf16(afr[0][ks], bfr, acc[0][nt], 0, 0, 0);
            acc[1][nt] = __builtin_amdgcn_mfma_f32_16x16x32_bf16(afr[1][ks], bfr, acc[1][nt], 0, 0, 0);
        }
    }
}

// ---- GEMM: grid = NSTR stripes x `chunks` K-chunks, 256 threads ----
// chunk 0,1 partials -> out column-halves; chunk c>=2 -> wpart[(c-2)*PARTF]
template<bool BF16A>
__global__ __launch_bounds__(256, 2) void gemm_kernel(const float* __restrict__ X,
        const unsigned short* __restrict__ A, const float* __restrict__ R,
        float* __restrict__ out, float* __restrict__ wpart,
        int nchunks, int kch) {
    __shared__ unsigned char Bs0[32 * 256];  // [n:32][k:128] bf16, XOR-swizzled
    __shared__ unsigned char Bs1[32 * 256];

    const int tid = threadIdx.x;
    const int w = tid >> 6;          // wave 0..3 -> M rows [32w, 32w+32)
    const int l = tid & 63;
    const int ln = l & 15, lg = l >> 4;
    const int chunk = blockIdx.x / NSTR;
    const int nb = blockIdx.x % NSTR;
    const int n0 = nb * BNW;
    const int kbase = chunk * kch;
    const int nsi = kch / KST;

    // B staging map: thread -> (k pair, n pair)
    const int kq = (tid >> 4) * 2;   // 0..30 even
    const int nq = (tid & 15) * 2;   // 0..30 even
    const float* bptr = R + (size_t)(kbase + kq) * NV + (n0 + nq);
    const int sw0 = (nq & 7) << 4;
    const int sw1 = ((nq + 1) & 7) << 4;

    size_t arow0, arow1;
    if (BF16A) {
        arow0 = (size_t)(w * 32 + ln) * NV + kbase + lg * 8;
        arow1 = arow0 + (size_t)16 * NV;
    } else {
        arow0 = (size_t)(w * 32 + ln) * NPIX + kbase + lg * 8;
        arow1 = arow0 + (size_t)16 * NPIX;
    }

    f32x4 acc[2][2];
    #pragma unroll
    for (int a = 0; a < 2; ++a)
        #pragma unroll
        for (int b = 0; b < 2; ++b) {
            acc[a][b][0] = 0.f; acc[a][b][1] = 0.f;
            acc[a][b][2] = 0.f; acc[a][b][3] = 0.f;
        }

    float2 ring0[8], ring1[8];
    sload(bptr, ring0);                       // step 0
    sload(bptr, ring1);                       // step 1
    wstage(Bs0, ring0, kq, nq, sw0, sw1);     // stage step 0
    __syncthreads();

    #pragma unroll 1
    for (int it = 0; it < nsi / 2; ++it) {
        const int s = it * 2;
        if (s + 2 < nsi) sload(bptr, ring0);                  // prefetch step s+2
        compute_step<BF16A>(Bs0, A, X, arow0, arow1, ln, lg, acc);  // step s
        arow0 += KST; arow1 += KST;
        wstage(Bs1, ring1, kq, nq, sw0, sw1);                 // stage step s+1
        __syncthreads();
        if (s + 3 < nsi) sload(bptr, ring1);                  // prefetch step s+3
        compute_step<BF16A>(Bs1, A, X, arow0, arow1, ln, lg, acc);  // step s+1
        arow0 += KST; arow1 += KST;
        if (s + 2 < nsi) wstage(Bs0, ring0, kq, nq, sw0, sw1);// stage step s+2
        __syncthreads();
    }

    // store raw partial sums
    float* dst;
    size_t rstride;
    if (chunk < 2) { dst = out + (size_t)chunk * NV; rstride = NPIX; }
    else           { dst = wpart + (size_t)(chunk - 2) * PARTF; rstride = NV; }
    #pragma unroll
    for (int mt = 0; mt < 2; ++mt) {
        const int mbase = w * 32 + mt * 16 + lg * 4;
        #pragma unroll
        for (int nt = 0; nt < 2; ++nt) {
            const size_t cb = (size_t)(n0 + nt * 16 + ln);
            #pragma unroll
            for (int j = 0; j < 4; ++j)
                dst[(size_t)(mbase + j) * rstride + cb] = acc[mt][nt][j];
        }
    }
}

// ---- reduce: out[:, :6144] = clip(sum of partials), out[:, 6144:] = 0 ----
__global__ __launch_bounds__(256) void reduce_kernel(float* __restrict__ out,
        const float* __restrict__ wpart, int nextra) {
    int q = blockIdx.x * 256 + threadIdx.x;   // 0 .. 196607 (exact)
    int m = q / (NV / 4);
    int r = q % (NV / 4);
    size_t base = (size_t)m * NPIX + r * 4;
    f32x4 a = *(f32x4*)(out + base);
    f32x4 b = *(f32x4*)(out + base + NV);
    #pragma unroll
    for (int i = 0; i < 4; ++i) a[i] += b[i];
    #pragma unroll 1
    for (int p = 0; p < nextra; ++p) {
        f32x4 c = *(const f32x4*)(wpart + (size_t)p * PARTF + (size_t)m * NV + r * 4);
        #pragma unroll
        for (int i = 0; i < 4; ++i) a[i] += c[i];
    }
    f32x4 cz, z;
    #pragma unroll
    for (int i = 0; i < 4; ++i) {
        cz[i] = fminf(fmaxf(a[i], 0.f), 1.f);
        z[i] = 0.f;
    }
    *(f32x4*)(out + base) = cz;
    *(f32x4*)(out + base + NV) = z;
}

extern "C" void kernel_launch(void* const* d_in, const int* in_sizes, int n_in,
                              void* d_out, int out_size, void* d_ws, size_t ws_size,
                              hipStream_t stream) {
    const float* x = (const float*)d_in[0];   // (8,16,12288) fp32 -> A rows [128][12288]
    const float* R = (const float*)d_in[1];   // (6144,6144) fp32
    float* out = (float*)d_out;               // (8,16,12288) fp32

    const size_t abytes = (size_t)MR * NV * 2;         // 1.5MB bf16 A (256-aligned)
    const bool use_ws = ws_size >= abytes;
    int chunks = 2;
    float* wpart = nullptr;
    if (use_ws) {
        size_t rem = ws_size - abytes;
        if      (rem >= 6 * PARTF * 4) chunks = 8;     // 18MB of partial slots
        else if (rem >= 2 * PARTF * 4) chunks = 4;     // 6MB
        wpart = (float*)((char*)d_ws + abytes);
    }
    const int kch = NV / chunks;

    if (use_ws) {
        unsigned short* abf = (unsigned short*)d_ws;
        prep_kernel<<<(MR * NV / 8) / 256, 256, 0, stream>>>(x, abf);
        gemm_kernel<true><<<NSTR * chunks, 256, 0, stream>>>(x, abf, R, out, wpart, chunks, kch);
    } else {
        gemm_kernel<false><<<NSTR * chunks, 256, 0, stream>>>(x, nullptr, R, out, wpart, chunks, kch);
    }
    reduce_kernel<<<(MR * NV / 4) / 256, 256, 0, stream>>>(out, wpart, chunks - 2);
}